// Round 1
// baseline (192.242 us; speedup 1.0000x reference)
//
#include <hip/hip_runtime.h>
#include <math.h>

#define B_SZ 256
#define N_TOK 5000
#define DM 128
#define DC 384
#define DK 128

// ---------------------------------------------------------------------------
// Kernel A: per-b projection, f64 accumulation (tiny: ~34 MFLOP total).
//   Q[b]  = Wq @ ctxt[b] + bq          (f64 acc, kept in f64 LDS)
//   v[b]  = Wk^T @ Q[b]                (f64 acc, rounded to f32)
//   c[b]  = Q[b] . bk                  (f64 acc, rounded to f32)
// ---------------------------------------------------------------------------
__global__ __launch_bounds__(128) void proj_kernel(
    const float* __restrict__ ctxt, const float* __restrict__ Wq,
    const float* __restrict__ bq, const float* __restrict__ Wk,
    const float* __restrict__ bk, float* __restrict__ v,
    float* __restrict__ c) {
  const int b = blockIdx.x;
  const int t = threadIdx.x;  // 0..127
  __shared__ float s_ctxt[DC];
  __shared__ double s_Q[DK];

  for (int i = t; i < DC; i += 128) s_ctxt[i] = ctxt[b * DC + i];
  __syncthreads();

  // Q[t] in f64
  double acc = (double)bq[t];
  const float* wrow = Wq + (size_t)t * DC;
  for (int cc = 0; cc < DC; ++cc) acc += (double)wrow[cc] * (double)s_ctxt[cc];
  s_Q[t] = acc;
  __syncthreads();

  // v[m=t] = sum_k Q[k] * Wk[k, t]   (coalesced over t)
  double vm = 0.0;
  for (int k = 0; k < DK; ++k) vm += s_Q[k] * (double)Wk[(size_t)k * DM + t];
  v[b * DM + t] = (float)vm;

  if (t == 0) {
    double cb = 0.0;
    for (int k = 0; k < DK; ++k) cb += s_Q[k] * (double)bk[k];
    c[b] = (float)cb;
  }
}

// ---------------------------------------------------------------------------
// Kernel B: streaming scores. One 32-lane group per token row:
//   lane l loads emb[b,n, 4l..4l+3] (512B contiguous per half-wave),
//   dot with v[b], shuffle-tree reduce, t = 10*tanh(u/sqrt(128)+..) + mask.
// Writes t into d_out (in-place softmax afterwards).
// ---------------------------------------------------------------------------
__global__ __launch_bounds__(256) void score_kernel(
    const float* __restrict__ emb, const float* __restrict__ mask,
    const float* __restrict__ v, const float* __restrict__ c,
    float* __restrict__ out) {
  const int b = blockIdx.y;
  const int nstart = blockIdx.x * 625;  // 8 chunks of 625 rows
  const int nend = nstart + 625;
  const int tid = threadIdx.x;
  const int wave = tid >> 6;
  const int lane = tid & 63;
  const int half = lane >> 5;
  const int l = lane & 31;

  const float4 vv = *reinterpret_cast<const float4*>(v + b * DM + 4 * l);
  const float cb = c[b];
  const float inv_sqrt = 0.08838834764831845f;  // 1/sqrt(128)

  const float* embb = emb + (size_t)b * N_TOK * DM;
  const float* maskb = mask + (size_t)b * N_TOK;
  float* outb = out + (size_t)b * N_TOK;

  for (int n0 = nstart + wave * 2 + half; n0 < nend; n0 += 8) {
    float4 e = *reinterpret_cast<const float4*>(embb + (size_t)n0 * DM + 4 * l);
    float d = e.x * vv.x + e.y * vv.y + e.z * vv.z + e.w * vv.w;
    d += __shfl_xor(d, 1);
    d += __shfl_xor(d, 2);
    d += __shfl_xor(d, 4);
    d += __shfl_xor(d, 8);
    d += __shfl_xor(d, 16);
    if (l == 0) {
      float u = (d + cb) * inv_sqrt;
      outb[n0] = 10.0f * tanhf(u) + maskb[n0];
    }
  }
}

// ---------------------------------------------------------------------------
// Kernel C: per-b softmax over 5000 scores, in-place on d_out via LDS.
// ---------------------------------------------------------------------------
__global__ __launch_bounds__(256) void softmax_kernel(float* __restrict__ out) {
  const int b = blockIdx.x;
  const int tid = threadIdx.x;
  __shared__ float s[N_TOK];
  __shared__ float red[256];
  float* row = out + (size_t)b * N_TOK;

  float local_max = -1e30f;
  for (int i = tid; i < N_TOK; i += 256) {
    float x = row[i];
    s[i] = x;
    local_max = fmaxf(local_max, x);
  }
  red[tid] = local_max;
  __syncthreads();
  for (int off = 128; off > 0; off >>= 1) {
    if (tid < off) red[tid] = fmaxf(red[tid], red[tid + off]);
    __syncthreads();
  }
  const float mx = red[0];
  __syncthreads();

  float local_sum = 0.0f;
  for (int i = tid; i < N_TOK; i += 256) {
    float e = expf(s[i] - mx);
    s[i] = e;
    local_sum += e;
  }
  red[tid] = local_sum;
  __syncthreads();
  for (int off = 128; off > 0; off >>= 1) {
    if (tid < off) red[tid] += red[tid + off];
    __syncthreads();
  }
  const float inv = 1.0f / red[0];

  for (int i = tid; i < N_TOK; i += 256) row[i] = s[i] * inv;
}

extern "C" void kernel_launch(void* const* d_in, const int* in_sizes, int n_in,
                              void* d_out, int out_size, void* d_ws,
                              size_t ws_size, hipStream_t stream) {
  const float* ctxt = (const float*)d_in[0];  // [B,1,384]
  const float* emb  = (const float*)d_in[1];  // [B,5000,128]
  const float* mask = (const float*)d_in[2];  // [B,1,5000]
  const float* Wq   = (const float*)d_in[3];  // [128,384]
  const float* bq   = (const float*)d_in[4];  // [128]
  const float* Wk   = (const float*)d_in[5];  // [128,128]
  const float* bk   = (const float*)d_in[6];  // [128]
  float* out = (float*)d_out;                 // [B,1,5000]

  float* v = (float*)d_ws;          // [B,128]
  float* c = v + B_SZ * DM;         // [B]

  proj_kernel<<<B_SZ, 128, 0, stream>>>(ctxt, Wq, bq, Wk, bk, v, c);
  score_kernel<<<dim3(8, B_SZ), 256, 0, stream>>>(emb, mask, v, c, out);
  softmax_kernel<<<B_SZ, 256, 0, stream>>>(out);
}

// Round 2
// 164.919 us; speedup vs baseline: 1.1657x; 1.1657x over previous
//
#include <hip/hip_runtime.h>
#include <math.h>

#define B_SZ 256
#define N_TOK 5000
#define DM 128
#define DC 384
#define DK 128
#define NBLK 8     // score blocks per batch row
#define CHUNK 625  // token rows per score block

// ---------------------------------------------------------------------------
// Kernel A: per-b projection, f64 accumulation (tiny: ~34 MFLOP total).
//   Q[b]  = Wq @ ctxt[b] + bq          (f64 acc, kept in f64 LDS)
//   v[b]  = Wk^T @ Q[b]                (f64 acc, rounded to f32)
//   c[b]  = Q[b] . bk                  (f64 acc, rounded to f32)
// ---------------------------------------------------------------------------
__global__ __launch_bounds__(128) void proj_kernel(
    const float* __restrict__ ctxt, const float* __restrict__ Wq,
    const float* __restrict__ bq, const float* __restrict__ Wk,
    const float* __restrict__ bk, float* __restrict__ v,
    float* __restrict__ c) {
  const int b = blockIdx.x;
  const int t = threadIdx.x;  // 0..127
  __shared__ float s_ctxt[DC];
  __shared__ double s_Q[DK];

  for (int i = t; i < DC; i += 128) s_ctxt[i] = ctxt[b * DC + i];
  __syncthreads();

  // Q[t] in f64, 2-way ILP to halve the dependent-FMA chain
  double acc0 = (double)bq[t], acc1 = 0.0;
  const float* wrow = Wq + (size_t)t * DC;
  for (int i = 0; i < DC; i += 2) {
    acc0 += (double)wrow[i] * (double)s_ctxt[i];
    acc1 += (double)wrow[i + 1] * (double)s_ctxt[i + 1];
  }
  s_Q[t] = acc0 + acc1;
  __syncthreads();

  // v[m=t] = sum_k Q[k] * Wk[k, t]   (coalesced over t)
  double v0 = 0.0, v1 = 0.0;
  for (int k = 0; k < DK; k += 2) {
    v0 += s_Q[k] * (double)Wk[(size_t)k * DM + t];
    v1 += s_Q[k + 1] * (double)Wk[(size_t)(k + 1) * DM + t];
  }
  v[b * DM + t] = (float)(v0 + v1);

  if (t == 0) {
    double cb = 0.0;
    for (int k = 0; k < DK; ++k) cb += s_Q[k] * (double)bk[k];
    c[b] = (float)cb;
  }
}

// ---------------------------------------------------------------------------
// Kernel B: streaming scores + exp + deterministic per-block partial sum.
// 16 lanes per token row (each lane: 32 B = 2x float4), 4 rows per wave-iter.
// u = 10*tanh(dot/sqrt(128)) + mask is bounded => exp without max-subtraction
// is algebraically identical to softmax's exp(u - max).
// ---------------------------------------------------------------------------
__global__ __launch_bounds__(256) void score_kernel(
    const float* __restrict__ emb, const float* __restrict__ mask,
    const float* __restrict__ v, const float* __restrict__ c,
    float* __restrict__ out, float* __restrict__ partial) {
  const int b = blockIdx.y;
  const int nstart = blockIdx.x * CHUNK;
  const int nend = nstart + CHUNK;
  const int tid = threadIdx.x;
  const int wave = tid >> 6;
  const int lane = tid & 63;
  const int q = lane >> 4;   // quarter-wave: which of 4 rows
  const int cc = lane & 15;  // 16 lanes cover one 512 B row

  const float4 vv0 = *reinterpret_cast<const float4*>(v + b * DM + 8 * cc);
  const float4 vv1 = *reinterpret_cast<const float4*>(v + b * DM + 8 * cc + 4);
  const float cb = c[b];
  const float inv_sqrt = 0.08838834764831845f;  // 1/sqrt(128)

  const float* embb = emb + (size_t)b * N_TOK * DM;
  const float* maskb = mask + (size_t)b * N_TOK;
  float* outb = out + (size_t)b * N_TOK;

  float lsum = 0.0f;
#pragma unroll 2
  for (int it = 0; it < 40; ++it) {  // 40*16 = 640 >= 625, tail guarded
    const int r = nstart + it * 16 + wave * 4 + q;
    if (r < nend) {  // whole 16-lane quarter uniformly valid/invalid
      const float* row = embb + (size_t)r * DM + 8 * cc;
      const float4 e0 = *reinterpret_cast<const float4*>(row);
      const float4 e1 = *reinterpret_cast<const float4*>(row + 4);
      float d = e0.x * vv0.x + e0.y * vv0.y + e0.z * vv0.z + e0.w * vv0.w +
                e1.x * vv1.x + e1.y * vv1.y + e1.z * vv1.z + e1.w * vv1.w;
      d += __shfl_xor(d, 1);
      d += __shfl_xor(d, 2);
      d += __shfl_xor(d, 4);
      d += __shfl_xor(d, 8);
      if (cc == 0) {
        const float u = (d + cb) * inv_sqrt;
        const float t = 10.0f * tanhf(u) + maskb[r];
        const float e = expf(t);
        outb[r] = e;
        lsum += e;
      }
    }
  }
  // fold the 4 per-quarter partials (cc==0 lanes) down to lane 0
  lsum += __shfl_xor(lsum, 16);
  lsum += __shfl_xor(lsum, 32);
  __shared__ float red[4];
  if (lane == 0) red[wave] = lsum;
  __syncthreads();
  if (tid == 0) {
    // fixed-order sum over the 4 waves -> deterministic partial
    partial[b * NBLK + blockIdx.x] = red[0] + red[1] + red[2] + red[3];
  }
}

// ---------------------------------------------------------------------------
// Kernel C: normalize. Sums the 8 per-block partials in fixed order
// (deterministic), scales the L3-hot e values.
// ---------------------------------------------------------------------------
__global__ __launch_bounds__(256) void norm_kernel(
    float* __restrict__ out, const float* __restrict__ partial) {
  const int b = blockIdx.y;
  const int nstart = blockIdx.x * CHUNK;
  float s = 0.0f;
#pragma unroll
  for (int i = 0; i < NBLK; ++i) s += partial[b * NBLK + i];
  const float inv = 1.0f / s;
  float* outb = out + (size_t)b * N_TOK + nstart;
  for (int i = threadIdx.x; i < CHUNK; i += 256) outb[i] *= inv;
}

extern "C" void kernel_launch(void* const* d_in, const int* in_sizes, int n_in,
                              void* d_out, int out_size, void* d_ws,
                              size_t ws_size, hipStream_t stream) {
  const float* ctxt = (const float*)d_in[0];  // [B,1,384]
  const float* emb  = (const float*)d_in[1];  // [B,5000,128]
  const float* mask = (const float*)d_in[2];  // [B,1,5000]
  const float* Wq   = (const float*)d_in[3];  // [128,384]
  const float* bq   = (const float*)d_in[4];  // [128]
  const float* Wk   = (const float*)d_in[5];  // [128,128]
  const float* bk   = (const float*)d_in[6];  // [128]
  float* out = (float*)d_out;                 // [B,1,5000]

  float* v = (float*)d_ws;                 // [B,128]
  float* c = v + B_SZ * DM;                // [B]
  float* partial = c + B_SZ;               // [B, NBLK]

  proj_kernel<<<B_SZ, 128, 0, stream>>>(ctxt, Wq, bq, Wk, bk, v, c);
  score_kernel<<<dim3(NBLK, B_SZ), 256, 0, stream>>>(emb, mask, v, c, out,
                                                     partial);
  norm_kernel<<<dim3(NBLK, B_SZ), 256, 0, stream>>>(out, partial);
}

// Round 3
// 154.352 us; speedup vs baseline: 1.2455x; 1.0685x over previous
//
#include <hip/hip_runtime.h>
#include <math.h>

#define B_SZ 256
#define N_TOK 5000
#define DM 128
#define DC 384
#define DK 128
#define NBLK 8     // score blocks per batch row
#define CHUNK 625  // token rows per score block

// ---------------------------------------------------------------------------
// Kernel A: per-b projection, f64 accumulation (tiny: ~34 MFLOP total).
//   Q[b]  = Wq @ ctxt[b] + bq          (f64 acc, kept in f64 LDS)
//   v[b]  = Wk^T @ Q[b]                (f64 acc, rounded to f32)
//   c[b]  = Q[b] . bk                  (f64 acc, rounded to f32)
// ---------------------------------------------------------------------------
__global__ __launch_bounds__(128) void proj_kernel(
    const float* __restrict__ ctxt, const float* __restrict__ Wq,
    const float* __restrict__ bq, const float* __restrict__ Wk,
    const float* __restrict__ bk, float* __restrict__ v,
    float* __restrict__ c) {
  const int b = blockIdx.x;
  const int t = threadIdx.x;  // 0..127
  __shared__ float s_ctxt[DC];
  __shared__ double s_Q[DK];

  for (int i = t; i < DC; i += 128) s_ctxt[i] = ctxt[b * DC + i];
  __syncthreads();

  // Q[t] in f64, 2-way ILP to halve the dependent-FMA chain
  double acc0 = (double)bq[t], acc1 = 0.0;
  const float* wrow = Wq + (size_t)t * DC;
  for (int i = 0; i < DC; i += 2) {
    acc0 += (double)wrow[i] * (double)s_ctxt[i];
    acc1 += (double)wrow[i + 1] * (double)s_ctxt[i + 1];
  }
  s_Q[t] = acc0 + acc1;
  __syncthreads();

  // v[m=t] = sum_k Q[k] * Wk[k, t]   (coalesced over t)
  double v0 = 0.0, v1 = 0.0;
  for (int k = 0; k < DK; k += 2) {
    v0 += s_Q[k] * (double)Wk[(size_t)k * DM + t];
    v1 += s_Q[k + 1] * (double)Wk[(size_t)(k + 1) * DM + t];
  }
  v[b * DM + t] = (float)(v0 + v1);

  if (t == 0) {
    double cb = 0.0;
    for (int k = 0; k < DK; ++k) cb += s_Q[k] * (double)bk[k];
    c[b] = (float)cb;
  }
}

// ---------------------------------------------------------------------------
// Kernel B: two-phase. Phase 1 streams emb, computes raw dots into LDS
// (no transcendentals in the hot loop). Phase 2 (full-width lanes) applies
// tanh-clip + mask + exp, writes e, reduces the block partial sum.
// 16 lanes per row; lane cc loads bytes [16cc,16cc+16) and [256+16cc,...)
// so every VMEM instruction covers dense contiguous 256B segments.
// ---------------------------------------------------------------------------
__global__ __launch_bounds__(256) void score_kernel(
    const float* __restrict__ emb, const float* __restrict__ mask,
    const float* __restrict__ v, const float* __restrict__ c,
    float* __restrict__ out, float* __restrict__ partial) {
  const int b = blockIdx.y;
  const int nstart = blockIdx.x * CHUNK;
  const int tid = threadIdx.x;
  const int wave = tid >> 6;
  const int lane = tid & 63;
  const int q = lane >> 4;   // quarter-wave: which of 4 rows
  const int cc = lane & 15;  // 16 lanes cover one 512 B row

  __shared__ float s_d[CHUNK];
  __shared__ float s_red[256];

  const float4 vv0 = *reinterpret_cast<const float4*>(v + b * DM + 4 * cc);
  const float4 vv1 =
      *reinterpret_cast<const float4*>(v + b * DM + 64 + 4 * cc);

  const float* embb = emb + (size_t)b * N_TOK * DM;
  const float* p0 = embb + (size_t)(nstart + wave * 4 + q) * DM + 4 * cc;

  // main loop: 39 iterations x 16 rows/block-iter = 624 rows, no guard
#pragma unroll 2
  for (int it = 0; it < 39; ++it) {
    const float* p = p0 + (size_t)it * 16 * DM;
    const float4 e0 = *reinterpret_cast<const float4*>(p);
    const float4 e1 = *reinterpret_cast<const float4*>(p + 64);
    float d = e0.x * vv0.x + e0.y * vv0.y + e0.z * vv0.z + e0.w * vv0.w +
              e1.x * vv1.x + e1.y * vv1.y + e1.z * vv1.z + e1.w * vv1.w;
    d += __shfl_xor(d, 1);
    d += __shfl_xor(d, 2);
    d += __shfl_xor(d, 4);
    d += __shfl_xor(d, 8);
    if (cc == 0) s_d[it * 16 + wave * 4 + q] = d;
  }
  // epilogue: row 624 (each quarter of wave 0 redundantly computes it)
  if (wave == 0) {
    const float* p = embb + (size_t)(nstart + 624) * DM + 4 * cc;
    const float4 e0 = *reinterpret_cast<const float4*>(p);
    const float4 e1 = *reinterpret_cast<const float4*>(p + 64);
    float d = e0.x * vv0.x + e0.y * vv0.y + e0.z * vv0.z + e0.w * vv0.w +
              e1.x * vv1.x + e1.y * vv1.y + e1.z * vv1.z + e1.w * vv1.w;
    d += __shfl_xor(d, 1);
    d += __shfl_xor(d, 2);
    d += __shfl_xor(d, 4);
    d += __shfl_xor(d, 8);
    if (lane == 0) s_d[624] = d;
  }
  __syncthreads();

  // phase 2: full-width transcendentals + partial sum (same math as before)
  const float cb = c[b];
  const float inv_sqrt = 0.08838834764831845f;  // 1/sqrt(128)
  const float* maskb = mask + (size_t)b * N_TOK + nstart;
  float* outb = out + (size_t)b * N_TOK + nstart;
  float lsum = 0.0f;
  for (int i = tid; i < CHUNK; i += 256) {
    const float u = (s_d[i] + cb) * inv_sqrt;
    const float t = 10.0f * tanhf(u) + maskb[i];
    const float e = expf(t);
    outb[i] = e;
    lsum += e;
  }
  s_red[tid] = lsum;
  __syncthreads();
  for (int off = 128; off > 0; off >>= 1) {
    if (tid < off) s_red[tid] += s_red[tid + off];
    __syncthreads();
  }
  if (tid == 0) partial[b * NBLK + blockIdx.x] = s_red[0];
}

// ---------------------------------------------------------------------------
// Kernel C: normalize. Sums the 8 per-block partials in fixed order
// (deterministic), scales the L3-hot e values.
// ---------------------------------------------------------------------------
__global__ __launch_bounds__(256) void norm_kernel(
    float* __restrict__ out, const float* __restrict__ partial) {
  const int b = blockIdx.y;
  const int nstart = blockIdx.x * CHUNK;
  float s = 0.0f;
#pragma unroll
  for (int i = 0; i < NBLK; ++i) s += partial[b * NBLK + i];
  const float inv = 1.0f / s;
  float* outb = out + (size_t)b * N_TOK + nstart;
  for (int i = threadIdx.x; i < CHUNK; i += 256) outb[i] *= inv;
}

extern "C" void kernel_launch(void* const* d_in, const int* in_sizes, int n_in,
                              void* d_out, int out_size, void* d_ws,
                              size_t ws_size, hipStream_t stream) {
  const float* ctxt = (const float*)d_in[0];  // [B,1,384]
  const float* emb  = (const float*)d_in[1];  // [B,5000,128]
  const float* mask = (const float*)d_in[2];  // [B,1,5000]
  const float* Wq   = (const float*)d_in[3];  // [128,384]
  const float* bq   = (const float*)d_in[4];  // [128]
  const float* Wk   = (const float*)d_in[5];  // [128,128]
  const float* bk   = (const float*)d_in[6];  // [128]
  float* out = (float*)d_out;                 // [B,1,5000]

  float* v = (float*)d_ws;                 // [B,128]
  float* c = v + B_SZ * DM;                // [B]
  float* partial = c + B_SZ;               // [B, NBLK]

  proj_kernel<<<B_SZ, 128, 0, stream>>>(ctxt, Wq, bq, Wk, bk, v, c);
  score_kernel<<<dim3(NBLK, B_SZ), 256, 0, stream>>>(emb, mask, v, c, out,
                                                     partial);
  norm_kernel<<<dim3(NBLK, B_SZ), 256, 0, stream>>>(out, partial);
}